// Round 6
// baseline (368.790 us; speedup 1.0000x reference)
//
#include <hip/hip_runtime.h>

#define N_IMG 4
#define C_CH  256
#define FH    100
#define FW    152
#define CHW   (C_CH * FH * FW)
#define OUT_PER_ROI (C_CH * 7 * 7)   // 12544
#define SCALE 0.0625f
#define H_ROW_BYTES (FW * C_CH * 2)  // 77824  (f16 NHWC feature row)
#define H_CH_BYTES  (C_CH * 2)       // 512    (one (y,x) cell, f16)
#define CPAD 260                     // padded channel stride (floats); 1040 B rows

typedef float    f4 __attribute__((ext_vector_type(4)));
typedef _Float16 h4 __attribute__((ext_vector_type(4)));

// ---------------- Kernel 0: bucket ROIs by (image, 8x8 spatial cell) ----------
__global__ __launch_bounds__(256) void bin_rois(
    const float* __restrict__ rois, const int* __restrict__ bids, int R,
    int* __restrict__ order) {
  __shared__ int hist[256];
  __shared__ int base[256];
  for (int k = threadIdx.x; k < 256; k += 256) hist[k] = 0;
  __syncthreads();
  for (int r = threadIdx.x; r < R; r += 256) {
    const float cx = (rois[r * 4 + 0] + rois[r * 4 + 2]) * 0.5f * SCALE;
    const float cy = (rois[r * 4 + 1] + rois[r * 4 + 3]) * 0.5f * SCALE;
    int xb = (int)(cx * (8.0f / FW)); xb = xb < 0 ? 0 : (xb > 7 ? 7 : xb);
    int yb = (int)(cy * (8.0f / FH)); yb = yb < 0 ? 0 : (yb > 7 ? 7 : yb);
    const int key = (bids[r] << 6) | (yb << 3) | xb;
    atomicAdd(&hist[key], 1);
  }
  __syncthreads();
  if (threadIdx.x == 0) {
    int s = 0;
    for (int k = 0; k < 256; ++k) { base[k] = s; s += hist[k]; }
  }
  __syncthreads();
  for (int r = threadIdx.x; r < R; r += 256) {
    const float cx = (rois[r * 4 + 0] + rois[r * 4 + 2]) * 0.5f * SCALE;
    const float cy = (rois[r * 4 + 1] + rois[r * 4 + 3]) * 0.5f * SCALE;
    int xb = (int)(cx * (8.0f / FW)); xb = xb < 0 ? 0 : (xb > 7 ? 7 : xb);
    int yb = (int)(cy * (8.0f / FH)); yb = yb < 0 ? 0 : (yb > 7 ? 7 : yb);
    const int key = (bids[r] << 6) | (yb << 3) | xb;
    const int pos = atomicAdd(&base[key], 1);
    order[pos] = r;
  }
}

// ---------------- Kernel 1: NCHW f32 -> NHWC f16 transpose of features -------
__global__ __launch_bounds__(256) void transpose_nchw_nhwc(
    const float* __restrict__ in, _Float16* __restrict__ out) {
  const int x0 = blockIdx.x * 32;
  const int y  = blockIdx.y;
  const int b  = blockIdx.z;
  __shared__ float tile[32][C_CH + 4];
  const int chl = threadIdx.x & 31;
  const int xq  = threadIdx.x >> 5;
  const int x   = x0 + xq * 4;
  const bool inb = (x < FW);
  const float4* src4 = (const float4*)in;
#pragma unroll
  for (int cc = 0; cc < C_CH; cc += 32) {
    const int ch = cc + chl;
    float4 v = make_float4(0.f, 0.f, 0.f, 0.f);
    if (inb) v = src4[((size_t)b * C_CH + ch) * (FH * FW / 4) + y * (FW / 4) + (x >> 2)];
    tile[xq * 4 + 0][ch] = v.x;
    tile[xq * 4 + 1][ch] = v.y;
    tile[xq * 4 + 2][ch] = v.z;
    tile[xq * 4 + 3][ch] = v.w;
  }
  __syncthreads();
  const int chg = threadIdx.x & 63;
  const int xs  = threadIdx.x >> 6;
  _Float16* dstB = out + (((size_t)b * FH + y) * FW) * C_CH;
#pragma unroll
  for (int xi = 0; xi < 32; xi += 4) {
    const int xx = x0 + xi + xs;
    if (xx < FW) {
      const f4 v = *(const f4*)&tile[xi + xs][chg * 4];
      h4 hv;
      hv[0] = (_Float16)v[0]; hv[1] = (_Float16)v[1];
      hv[2] = (_Float16)v[2]; hv[3] = (_Float16)v[3];
      *(h4*)(dstB + (size_t)xx * C_CH + chg * 4) = hv;
    }
  }
}

// ---------------- Kernel 2: pipelined 2-ROI RoIAlign + 2x2 avg pool ----------
struct RoiW {
  float a0, a1;
  float q0[8], q1[8];
};

// Compute weights and ISSUE all 32 gather loads into registers (no use yet).
__device__ __forceinline__ void roi_issue(
    const _Float16* __restrict__ feat, const float* __restrict__ rois,
    const int* __restrict__ bids, int r, int i, int cg,
    RoiW& W, h4 ld[32]) {
  const float x1 = rois[r * 4 + 0] * SCALE;
  const float y1 = rois[r * 4 + 1] * SCALE;
  const float x2 = rois[r * 4 + 2] * SCALE;
  const float y2 = rois[r * 4 + 3] * SCALE;
  const int   b  = bids[r];
  const float bw = fmaxf(x2 - x1 + 1.0f, 0.0f) * (1.0f / 7.0f);
  const float bh = fmaxf(y2 - y1 + 1.0f, 0.0f) * (1.0f / 7.0f);
  const float h   = y1 + (float)i * bh;
  const float hsf = fminf(fmaxf(floorf(h), 0.0f), (float)(FH - 2));
  const float hr  = h - hsf;
  const float mh  = (h >= 0.0f && h < (float)FH) ? 1.0f : 0.0f;
  W.a0 = (1.0f - hr) * mh;
  W.a1 = hr * mh;
  const char* fbb  = (const char*)feat + (size_t)b * CHW * 2;
  const int   row0 = (int)hsf * H_ROW_BYTES + cg * 8;
#pragma unroll
  for (int j = 0; j < 8; ++j) {
    const float w   = x1 + (float)j * bw;
    const float wsf = fminf(fmaxf(floorf(w), 0.0f), (float)(FW - 2));
    const float wr  = w - wsf;
    const float mw  = (w >= 0.0f && w < (float)FW) ? 1.0f : 0.0f;
    W.q0[j] = (1.0f - wr) * mw;
    W.q1[j] = wr * mw;
    const int o0 = row0 + (int)wsf * H_CH_BYTES;
    ld[4 * j + 0] = *(const h4*)(fbb + o0);
    ld[4 * j + 1] = *(const h4*)(fbb + o0 + H_CH_BYTES);
    ld[4 * j + 2] = *(const h4*)(fbb + o0 + H_ROW_BYTES);
    ld[4 * j + 3] = *(const h4*)(fbb + o0 + H_ROW_BYTES + H_CH_BYTES);
  }
}

// Consume the 32 loads (backend inserts vmcnt waits here), stage row in LDS.
__device__ __forceinline__ void roi_compute_store(
    const RoiW& W, const h4 ld[32], float* lbase) {
#pragma unroll
  for (int j = 0; j < 8; ++j) {
    const f4 g00 = __builtin_convertvector(ld[4 * j + 0], f4);
    const f4 g01 = __builtin_convertvector(ld[4 * j + 1], f4);
    const f4 g10 = __builtin_convertvector(ld[4 * j + 2], f4);
    const f4 g11 = __builtin_convertvector(ld[4 * j + 3], f4);
    const f4 s = (g00 * W.q0[j] + g01 * W.q1[j]) * W.a0 +
                 (g10 * W.q0[j] + g11 * W.q1[j]) * W.a1;
    *(f4*)(lbase + j * CPAD) = s;
  }
}

// Output-linear pooled writeback (coalesced float4 NT stores).
__device__ __forceinline__ void roi_phase2(
    const float* __restrict__ smp, float* __restrict__ outr, int tid) {
  f4* dst = (f4*)outr;
  const int g0 = tid * 4;
  int c   = (g0 * 669) >> 15;          // exact g/49 for g < 2048
  int rem = g0 - c * 49;
#pragma unroll
  for (int k = 0; k < 7; ++k) {
    const int idx = tid + k * 512;
    if (idx < (OUT_PER_ROI / 4)) {
      f4 v;
      int cc = c, rr = rem;
#pragma unroll
      for (int e = 0; e < 4; ++e) {
        const int p    = (rr * 37) >> 8;   // exact rr/7 for rr < 49
        const int j    = rr - p * 7;
        const int base = (p * 8 + j) * CPAD + cc;
        v[e] = (smp[base] + smp[base + CPAD] +
                smp[base + 8 * CPAD] + smp[base + 9 * CPAD]) * 0.25f;
        if (++rr == 49) { rr = 0; ++cc; }
      }
      __builtin_nontemporal_store(v, dst + idx);
    }
    rem += 39; c += 41;
    if (rem >= 49) { rem -= 49; ++c; }
  }
}

// LDS-only barrier: drain DS ops, do NOT drain vmcnt (keeps B's gathers in
// flight across the barrier — __syncthreads would emit vmcnt(0) and kill the
// pipeline; all cross-wave data here lives in LDS, so lgkmcnt(0) suffices).
#define LDS_BARRIER()                                    \
  do {                                                   \
    asm volatile("s_waitcnt lgkmcnt(0)" ::: "memory");   \
    __builtin_amdgcn_s_barrier();                        \
  } while (0)

__global__ __launch_bounds__(512, 4) void roialign_nhwc(
    const _Float16* __restrict__ feat, const float* __restrict__ rois,
    const int* __restrict__ bids, const int* __restrict__ order,
    int R, float* __restrict__ out) {
  const int nblk = (R + 1) >> 1;
  const int g    = blockIdx.x;
  const int swz  = ((nblk & 7) == 0) ? ((g & 7) * (nblk >> 3) + (g >> 3)) : g;
  const bool hasB = (2 * swz + 1 < R);   // block-uniform
  const int rA   = order[2 * swz + 0];
  const int rB   = hasB ? order[2 * swz + 1] : rA;
  const int tid  = threadIdx.x;
  const int cg   = tid & 63;             // channel group (4 ch)
  const int i    = tid >> 6;             // sample row 0..7 (wave-uniform)
  __shared__ float smp[64 * CPAD];       // 66,560 B -> 2 blocks/CU
  float* lbase = &smp[(i * 8) * CPAD + cg * 4];

  // --- ROI A: issue + compute + stage ---
  RoiW WA; h4 ldA[32];
  roi_issue(feat, rois, bids, rA, i, cg, WA, ldA);
  roi_compute_store(WA, ldA, lbase);

  // --- ROI B: issue now; latency hides under phase2(A) ---
  RoiW WB; h4 ldB[32];
  if (hasB) roi_issue(feat, rois, bids, rB, i, cg, WB, ldB);

  LDS_BARRIER();
  roi_phase2(smp, out + (size_t)rA * OUT_PER_ROI, tid);

  if (hasB) {
    LDS_BARRIER();                       // phase2(A) reads done before overwrite
    roi_compute_store(WB, ldB, lbase);
    LDS_BARRIER();                       // B staged before phase2(B) reads
    roi_phase2(smp, out + (size_t)rB * OUT_PER_ROI, tid);
  }
}

// ---------------- Host launch ----------------
extern "C" void kernel_launch(void* const* d_in, const int* in_sizes, int n_in,
                              void* d_out, int out_size, void* d_ws, size_t ws_size,
                              hipStream_t stream) {
  (void)n_in; (void)out_size; (void)ws_size;
  const float* features = (const float*)d_in[0];
  const float* rois     = (const float*)d_in[1];
  const int*   bids     = (const int*)d_in[2];
  float* out = (float*)d_out;
  const int R = in_sizes[1] / 4;  // 4000

  _Float16* nhwc  = (_Float16*)d_ws;                    // 31.1 MB (f16 NHWC)
  int*      order = (int*)((char*)d_ws + (64u << 20));  // 16 KB at +64 MB

  bin_rois<<<1, 256, 0, stream>>>(rois, bids, R, order);
  dim3 tgrid((FW + 31) / 32, FH, N_IMG);  // (5, 100, 4)
  transpose_nchw_nhwc<<<tgrid, 256, 0, stream>>>(features, nhwc);
  const int nblk = (R + 1) / 2;           // 2000 pair-blocks
  roialign_nhwc<<<nblk, 512, 0, stream>>>(nhwc, rois, bids, order, R, out);
}

// Round 7
// 290.951 us; speedup vs baseline: 1.2675x; 1.2675x over previous
//
#include <hip/hip_runtime.h>

#define N_IMG 4
#define C_CH  256
#define FH    100
#define FW    152
#define CHW   (C_CH * FH * FW)
#define OUT_PER_ROI (C_CH * 7 * 7)   // 12544
#define SCALE 0.0625f
#define H_ROW_BYTES (FW * C_CH * 2)  // 77824  (f16 NHWC feature row)
#define H_CH_BYTES  (C_CH * 2)       // 512    (one (y,x) cell, f16)
#define CP 260                       // LDS row stride (floats); 1040 B (16B-aligned)

typedef float    f4 __attribute__((ext_vector_type(4)));
typedef _Float16 h4 __attribute__((ext_vector_type(4)));

// ---------------- Kernel 0: bucket ROIs by (image, 8x8 spatial cell) ----------
__global__ __launch_bounds__(256) void bin_rois(
    const float* __restrict__ rois, const int* __restrict__ bids, int R,
    int* __restrict__ order) {
  __shared__ int hist[256];
  __shared__ int base[256];
  for (int k = threadIdx.x; k < 256; k += 256) hist[k] = 0;
  __syncthreads();
  for (int r = threadIdx.x; r < R; r += 256) {
    const float cx = (rois[r * 4 + 0] + rois[r * 4 + 2]) * 0.5f * SCALE;
    const float cy = (rois[r * 4 + 1] + rois[r * 4 + 3]) * 0.5f * SCALE;
    int xb = (int)(cx * (8.0f / FW)); xb = xb < 0 ? 0 : (xb > 7 ? 7 : xb);
    int yb = (int)(cy * (8.0f / FH)); yb = yb < 0 ? 0 : (yb > 7 ? 7 : yb);
    const int key = (bids[r] << 6) | (yb << 3) | xb;
    atomicAdd(&hist[key], 1);
  }
  __syncthreads();
  if (threadIdx.x == 0) {
    int s = 0;
    for (int k = 0; k < 256; ++k) { base[k] = s; s += hist[k]; }
  }
  __syncthreads();
  for (int r = threadIdx.x; r < R; r += 256) {
    const float cx = (rois[r * 4 + 0] + rois[r * 4 + 2]) * 0.5f * SCALE;
    const float cy = (rois[r * 4 + 1] + rois[r * 4 + 3]) * 0.5f * SCALE;
    int xb = (int)(cx * (8.0f / FW)); xb = xb < 0 ? 0 : (xb > 7 ? 7 : xb);
    int yb = (int)(cy * (8.0f / FH)); yb = yb < 0 ? 0 : (yb > 7 ? 7 : yb);
    const int key = (bids[r] << 6) | (yb << 3) | xb;
    const int pos = atomicAdd(&base[key], 1);
    order[pos] = r;
  }
}

// ---------------- Kernel 1: NCHW f32 -> NHWC f16 transpose of features -------
__global__ __launch_bounds__(256) void transpose_nchw_nhwc(
    const float* __restrict__ in, _Float16* __restrict__ out) {
  const int x0 = blockIdx.x * 32;
  const int y  = blockIdx.y;
  const int b  = blockIdx.z;
  __shared__ float tile[32][C_CH + 4];
  const int chl = threadIdx.x & 31;
  const int xq  = threadIdx.x >> 5;
  const int x   = x0 + xq * 4;
  const bool inb = (x < FW);
  const float4* src4 = (const float4*)in;
#pragma unroll
  for (int cc = 0; cc < C_CH; cc += 32) {
    const int ch = cc + chl;
    float4 v = make_float4(0.f, 0.f, 0.f, 0.f);
    if (inb) v = src4[((size_t)b * C_CH + ch) * (FH * FW / 4) + y * (FW / 4) + (x >> 2)];
    tile[xq * 4 + 0][ch] = v.x;
    tile[xq * 4 + 1][ch] = v.y;
    tile[xq * 4 + 2][ch] = v.z;
    tile[xq * 4 + 3][ch] = v.w;
  }
  __syncthreads();
  const int chg = threadIdx.x & 63;
  const int xs  = threadIdx.x >> 6;
  _Float16* dstB = out + (((size_t)b * FH + y) * FW) * C_CH;
#pragma unroll
  for (int xi = 0; xi < 32; xi += 4) {
    const int xx = x0 + xi + xs;
    if (xx < FW) {
      const f4 v = *(const f4*)&tile[xi + xs][chg * 4];
      h4 hv;
      hv[0] = (_Float16)v[0]; hv[1] = (_Float16)v[1];
      hv[2] = (_Float16)v[2]; hv[3] = (_Float16)v[3];
      *(h4*)(dstB + (size_t)xx * C_CH + chg * 4) = hv;
    }
  }
}

// ---------------- Kernel 2: RoIAlign + 2x2 avg pool, hp-staged (NHWC f16) ----
// 512 threads, one block per ROI (R5 structure). Wave i gathers sample row i
// (32 h4 loads in flight), computes bilinear in f32, and stages HORIZONTAL
// pair-sums hp[i][j] = x[i][j] + x[i][j+1] (j=0..6) in LDS [56][CP].
// Phase 2 pools vertically: out[p][j] = (hp[p][j] + hp[p+1][j]) * 0.25 —
// 2 LDS reads/element (was 4), pos == rr (no div-7), coalesced NT stores.
__global__ __launch_bounds__(512, 4) void roialign_nhwc(
    const _Float16* __restrict__ feat, const float* __restrict__ rois,
    const int* __restrict__ bids, const int* __restrict__ order,
    int R, float* __restrict__ out) {
  const int g  = blockIdx.x;
  const int r  = order[((R & 7) == 0) ? ((g & 7) * (R >> 3) + (g >> 3)) : g];
  const int cg = threadIdx.x & 63;       // channel group: channels 4*cg..4*cg+3
  const int i  = threadIdx.x >> 6;       // sample row 0..7 (wave-uniform)
  __shared__ float smp[56 * CP];         // 58,240 B -> 2 blocks/CU

  const float x1 = rois[r * 4 + 0] * SCALE;
  const float y1 = rois[r * 4 + 1] * SCALE;
  const float x2 = rois[r * 4 + 2] * SCALE;
  const float y2 = rois[r * 4 + 3] * SCALE;
  const int   b  = bids[r];
  const float bw = fmaxf(x2 - x1 + 1.0f, 0.0f) * (1.0f / 7.0f);
  const float bh = fmaxf(y2 - y1 + 1.0f, 0.0f) * (1.0f / 7.0f);

  // Row weights (wave-uniform).
  const float h   = y1 + (float)i * bh;
  const float hsf = fminf(fmaxf(floorf(h), 0.0f), (float)(FH - 2));
  const float hr  = h - hsf;
  const float mh  = (h >= 0.0f && h < (float)FH) ? 1.0f : 0.0f;
  const float a0  = (1.0f - hr) * mh;
  const float a1  = hr * mh;

  const char* fbb  = (const char*)feat + (size_t)b * CHW * 2;
  const int   row0 = (int)hsf * H_ROW_BYTES + cg * 8;

  float* lbase = &smp[(i * 7) * CP + cg * 4];

  f4 prev;
#pragma unroll
  for (int j = 0; j < 8; ++j) {
    const float w   = x1 + (float)j * bw;
    const float wsf = fminf(fmaxf(floorf(w), 0.0f), (float)(FW - 2));
    const float wr  = w - wsf;
    const float mw  = (w >= 0.0f && w < (float)FW) ? 1.0f : 0.0f;
    const float q0  = (1.0f - wr) * mw;
    const float q1  = wr * mw;
    const int   o0  = row0 + (int)wsf * H_CH_BYTES;
    const h4 h00 = *(const h4*)(fbb + o0);
    const h4 h01 = *(const h4*)(fbb + o0 + H_CH_BYTES);
    const h4 h10 = *(const h4*)(fbb + o0 + H_ROW_BYTES);
    const h4 h11 = *(const h4*)(fbb + o0 + H_ROW_BYTES + H_CH_BYTES);
    const f4 g00 = __builtin_convertvector(h00, f4);
    const f4 g01 = __builtin_convertvector(h01, f4);
    const f4 g10 = __builtin_convertvector(h10, f4);
    const f4 g11 = __builtin_convertvector(h11, f4);
    const f4 s = (g00 * q0 + g01 * q1) * a0 +
                 (g10 * q0 + g11 * q1) * a1;
    if (j > 0) *(f4*)(lbase + (j - 1) * CP) = prev + s;   // hp[i][j-1]
    prev = s;
  }

  __syncthreads();

  // Phase 2: pooled writeback, output-linear (coalesced float4 NT stores).
  // Output element g = c*49 + rr, rr = p*7 + j; hp pair at LDS rows rr, rr+7.
  f4* dst = (f4*)(out + (size_t)r * OUT_PER_ROI);
  const int g0 = (int)threadIdx.x * 4;
  int c   = (g0 * 669) >> 15;          // exact g/49 for g < 2048
  int rem = g0 - c * 49;
#pragma unroll
  for (int k = 0; k < 7; ++k) {
    const int idx = (int)threadIdx.x + k * 512;
    if (idx < (OUT_PER_ROI / 4)) {
      f4 v;
      int cc = c, rr = rem;
#pragma unroll
      for (int e = 0; e < 4; ++e) {
        const int base = rr * CP + cc;
        v[e] = (smp[base] + smp[base + 7 * CP]) * 0.25f;
        if (++rr == 49) { rr = 0; ++cc; }
      }
      __builtin_nontemporal_store(v, dst + idx);
    }
    rem += 39; c += 41;                 // advance by 2048 outputs
    if (rem >= 49) { rem -= 49; ++c; }
  }
}

// ---------------- Host launch ----------------
extern "C" void kernel_launch(void* const* d_in, const int* in_sizes, int n_in,
                              void* d_out, int out_size, void* d_ws, size_t ws_size,
                              hipStream_t stream) {
  (void)n_in; (void)out_size; (void)ws_size;
  const float* features = (const float*)d_in[0];
  const float* rois     = (const float*)d_in[1];
  const int*   bids     = (const int*)d_in[2];
  float* out = (float*)d_out;
  const int R = in_sizes[1] / 4;  // 4000

  _Float16* nhwc  = (_Float16*)d_ws;                    // 31.1 MB (f16 NHWC)
  int*      order = (int*)((char*)d_ws + (64u << 20));  // 16 KB at +64 MB

  bin_rois<<<1, 256, 0, stream>>>(rois, bids, R, order);
  dim3 tgrid((FW + 31) / 32, FH, N_IMG);  // (5, 100, 4)
  transpose_nchw_nhwc<<<tgrid, 256, 0, stream>>>(features, nhwc);
  roialign_nhwc<<<R, 512, 0, stream>>>(nhwc, rois, bids, order, R, out);
}

// Round 13
// 277.342 us; speedup vs baseline: 1.3297x; 1.0491x over previous
//
#include <hip/hip_runtime.h>

#define N_IMG 4
#define C_CH  256
#define FH    100
#define FW    152
#define CHW   (C_CH * FH * FW)
#define OUT_PER_ROI (C_CH * 7 * 7)   // 12544
#define SCALE 0.0625f
#define H_ROW_BYTES (FW * C_CH * 2)  // 77824  (f16 NHWC feature row)
#define H_CH_BYTES  (C_CH * 2)       // 512    (one (y,x) cell, f16)
#define CPH 260                      // f16 LDS row stride (elements) — MUST be >= C_CH=256.
                                     // 520 B rows (8-B aligned); 56*260*2 = 29,120 B LDS.

typedef float    f4 __attribute__((ext_vector_type(4)));
typedef _Float16 h4 __attribute__((ext_vector_type(4)));

// ---------------- Kernel 0: bucket ROIs by (image, 8x8 spatial cell) ----------
__global__ __launch_bounds__(256) void bin_rois(
    const float* __restrict__ rois, const int* __restrict__ bids, int R,
    int* __restrict__ order) {
  __shared__ int hist[256];
  __shared__ int base[256];
  for (int k = threadIdx.x; k < 256; k += 256) hist[k] = 0;
  __syncthreads();
  for (int r = threadIdx.x; r < R; r += 256) {
    const float cx = (rois[r * 4 + 0] + rois[r * 4 + 2]) * 0.5f * SCALE;
    const float cy = (rois[r * 4 + 1] + rois[r * 4 + 3]) * 0.5f * SCALE;
    int xb = (int)(cx * (8.0f / FW)); xb = xb < 0 ? 0 : (xb > 7 ? 7 : xb);
    int yb = (int)(cy * (8.0f / FH)); yb = yb < 0 ? 0 : (yb > 7 ? 7 : yb);
    const int key = (bids[r] << 6) | (yb << 3) | xb;
    atomicAdd(&hist[key], 1);
  }
  __syncthreads();
  if (threadIdx.x == 0) {
    int s = 0;
    for (int k = 0; k < 256; ++k) { base[k] = s; s += hist[k]; }
  }
  __syncthreads();
  for (int r = threadIdx.x; r < R; r += 256) {
    const float cx = (rois[r * 4 + 0] + rois[r * 4 + 2]) * 0.5f * SCALE;
    const float cy = (rois[r * 4 + 1] + rois[r * 4 + 3]) * 0.5f * SCALE;
    int xb = (int)(cx * (8.0f / FW)); xb = xb < 0 ? 0 : (xb > 7 ? 7 : xb);
    int yb = (int)(cy * (8.0f / FH)); yb = yb < 0 ? 0 : (yb > 7 ? 7 : yb);
    const int key = (bids[r] << 6) | (yb << 3) | xb;
    const int pos = atomicAdd(&base[key], 1);
    order[pos] = r;
  }
}

// ---------------- Kernel 1: NCHW f32 -> NHWC f16 transpose of features -------
__global__ __launch_bounds__(256) void transpose_nchw_nhwc(
    const float* __restrict__ in, _Float16* __restrict__ out) {
  const int x0 = blockIdx.x * 32;
  const int y  = blockIdx.y;
  const int b  = blockIdx.z;
  __shared__ float tile[32][C_CH + 4];
  const int chl = threadIdx.x & 31;
  const int xq  = threadIdx.x >> 5;
  const int x   = x0 + xq * 4;
  const bool inb = (x < FW);
  const float4* src4 = (const float4*)in;
#pragma unroll
  for (int cc = 0; cc < C_CH; cc += 32) {
    const int ch = cc + chl;
    float4 v = make_float4(0.f, 0.f, 0.f, 0.f);
    if (inb) v = src4[((size_t)b * C_CH + ch) * (FH * FW / 4) + y * (FW / 4) + (x >> 2)];
    tile[xq * 4 + 0][ch] = v.x;
    tile[xq * 4 + 1][ch] = v.y;
    tile[xq * 4 + 2][ch] = v.z;
    tile[xq * 4 + 3][ch] = v.w;
  }
  __syncthreads();
  const int chg = threadIdx.x & 63;
  const int xs  = threadIdx.x >> 6;
  _Float16* dstB = out + (((size_t)b * FH + y) * FW) * C_CH;
#pragma unroll
  for (int xi = 0; xi < 32; xi += 4) {
    const int xx = x0 + xi + xs;
    if (xx < FW) {
      const f4 v = *(const f4*)&tile[xi + xs][chg * 4];
      h4 hv;
      hv[0] = (_Float16)v[0]; hv[1] = (_Float16)v[1];
      hv[2] = (_Float16)v[2]; hv[3] = (_Float16)v[3];
      *(h4*)(dstB + (size_t)xx * C_CH + chg * 4) = hv;
    }
  }
}

// ---------------- Kernel 2: RoIAlign + 2x2 avg pool, f16-hp staged ----------
// 512 threads, one block per ROI. Wave i gathers sample row i (32 h4 loads in
// flight), bilinear in f32, stages HORIZONTAL pair-sums hp[i][j] as f16 in
// LDS [56][CPH] (29.1 KB). Phase 2: out = (hp[rr] + hp[rr+7]) * 0.25.
// __launch_bounds__(512,6) -> 3 blocks/CU, 24 waves/CU (was 16): more gather
// latency hiding. VGPR cap ~85 keeps the 32-load burst unspilled.
__global__ __launch_bounds__(512, 6) void roialign_nhwc(
    const _Float16* __restrict__ feat, const float* __restrict__ rois,
    const int* __restrict__ bids, const int* __restrict__ order,
    int R, float* __restrict__ out) {
  const int g  = blockIdx.x;
  const int r  = order[((R & 7) == 0) ? ((g & 7) * (R >> 3) + (g >> 3)) : g];
  const int cg = threadIdx.x & 63;       // channel group: channels 4*cg..4*cg+3
  const int i  = threadIdx.x >> 6;       // sample row 0..7 (wave-uniform)
  __shared__ _Float16 smp[56 * CPH];     // 29,120 B

  const float x1 = rois[r * 4 + 0] * SCALE;
  const float y1 = rois[r * 4 + 1] * SCALE;
  const float x2 = rois[r * 4 + 2] * SCALE;
  const float y2 = rois[r * 4 + 3] * SCALE;
  const int   b  = bids[r];
  const float bw = fmaxf(x2 - x1 + 1.0f, 0.0f) * (1.0f / 7.0f);
  const float bh = fmaxf(y2 - y1 + 1.0f, 0.0f) * (1.0f / 7.0f);

  // Row weights (wave-uniform).
  const float h   = y1 + (float)i * bh;
  const float hsf = fminf(fmaxf(floorf(h), 0.0f), (float)(FH - 2));
  const float hr  = h - hsf;
  const float mh  = (h >= 0.0f && h < (float)FH) ? 1.0f : 0.0f;
  const float a0  = (1.0f - hr) * mh;
  const float a1  = hr * mh;

  const char* fbb  = (const char*)feat + (size_t)b * CHW * 2;
  const int   row0 = (int)hsf * H_ROW_BYTES + cg * 8;

  _Float16* lbase = &smp[(i * 7) * CPH + cg * 4];   // byte off = i*3640 + cg*8: 8-B aligned

  f4 prev;
#pragma unroll
  for (int j = 0; j < 8; ++j) {
    const float w   = x1 + (float)j * bw;
    const float wsf = fminf(fmaxf(floorf(w), 0.0f), (float)(FW - 2));
    const float wr  = w - wsf;
    const float mw  = (w >= 0.0f && w < (float)FW) ? 1.0f : 0.0f;
    const float q0  = (1.0f - wr) * mw;
    const float q1  = wr * mw;
    const int   o0  = row0 + (int)wsf * H_CH_BYTES;
    const h4 h00 = *(const h4*)(fbb + o0);
    const h4 h01 = *(const h4*)(fbb + o0 + H_CH_BYTES);
    const h4 h10 = *(const h4*)(fbb + o0 + H_ROW_BYTES);
    const h4 h11 = *(const h4*)(fbb + o0 + H_ROW_BYTES + H_CH_BYTES);
    const f4 g00 = __builtin_convertvector(h00, f4);
    const f4 g01 = __builtin_convertvector(h01, f4);
    const f4 g10 = __builtin_convertvector(h10, f4);
    const f4 g11 = __builtin_convertvector(h11, f4);
    const f4 s = (g00 * q0 + g01 * q1) * a0 +
                 (g10 * q0 + g11 * q1) * a1;
    if (j > 0) {
      const f4 hp = prev + s;                       // hp[i][j-1]
      h4 hh;
      hh[0] = (_Float16)hp[0]; hh[1] = (_Float16)hp[1];
      hh[2] = (_Float16)hp[2]; hh[3] = (_Float16)hp[3];
      *(h4*)(lbase + (j - 1) * CPH) = hh;
    }
    prev = s;
  }

  __syncthreads();

  // Phase 2: pooled writeback, output-linear (coalesced float4 NT stores).
  // Output element g = c*49 + rr, rr = p*7 + j; hp pair at LDS rows rr, rr+7.
  f4* dst = (f4*)(out + (size_t)r * OUT_PER_ROI);
  const int g0 = (int)threadIdx.x * 4;
  int c   = (g0 * 669) >> 15;          // exact g/49 for g < 2048
  int rem = g0 - c * 49;
#pragma unroll
  for (int k = 0; k < 7; ++k) {
    const int idx = (int)threadIdx.x + k * 512;
    if (idx < (OUT_PER_ROI / 4)) {
      f4 v;
      int cc = c, rr = rem;
#pragma unroll
      for (int e = 0; e < 4; ++e) {
        const int base = rr * CPH + cc;
        v[e] = ((float)smp[base] + (float)smp[base + 7 * CPH]) * 0.25f;
        if (++rr == 49) { rr = 0; ++cc; }
      }
      __builtin_nontemporal_store(v, dst + idx);
    }
    rem += 39; c += 41;                 // advance by 2048 outputs
    if (rem >= 49) { rem -= 49; ++c; }
  }
}

// ---------------- Host launch ----------------
extern "C" void kernel_launch(void* const* d_in, const int* in_sizes, int n_in,
                              void* d_out, int out_size, void* d_ws, size_t ws_size,
                              hipStream_t stream) {
  (void)n_in; (void)out_size; (void)ws_size;
  const float* features = (const float*)d_in[0];
  const float* rois     = (const float*)d_in[1];
  const int*   bids     = (const int*)d_in[2];
  float* out = (float*)d_out;
  const int R = in_sizes[1] / 4;  // 4000

  _Float16* nhwc  = (_Float16*)d_ws;                    // 31.1 MB (f16 NHWC)
  int*      order = (int*)((char*)d_ws + (64u << 20));  // 16 KB at +64 MB

  bin_rois<<<1, 256, 0, stream>>>(rois, bids, R, order);
  dim3 tgrid((FW + 31) / 32, FH, N_IMG);  // (5, 100, 4)
  transpose_nchw_nhwc<<<tgrid, 256, 0, stream>>>(features, nhwc);
  roialign_nhwc<<<R, 512, 0, stream>>>(nhwc, rois, bids, order, R, out);
}